// Round 6
// baseline (239.592 us; speedup 1.0000x reference)
//
#include <hip/hip_runtime.h>

// Problem shape (from reference): B=32, C=256, H=W=64
#define BATCH 32
#define CHANS 256
#define HWSZ  4096                    // 64*64 floats per (b,c) slab
#define NSLAB (BATCH * CHANS)         // 8192 slabs
#define SLABS_PER_BLOCK 4
#define NBLOCKS (NSLAB / SLABS_PER_BLOCK)   // 2048 blocks = 8192 waves = exact fill
#define INV_COUNT (1.0f / 131072.0f)  // 1 / (B*H*W)
#define HIST_N 10000

typedef float f4 __attribute__((ext_vector_type(4)));

// Runs first: seed energy output with td_energy (atomic base) and hist.
__global__ __launch_bounds__(256) void init_small(
    const float* __restrict__ td_energy, const float* __restrict__ td_hist,
    float* __restrict__ out_energy, float* __restrict__ out_hist) {
    const int i = blockIdx.x * 256 + threadIdx.x;
    if (i < CHANS) out_energy[i] = td_energy[i];
    if (i < HIST_N) out_hist[i] = td_hist[i] + 1.0f;
}

// Each block: 4 contiguous slabs (64 KiB). 16 independent f4 loads per thread
// issued before any store (256 B MLP/thread), then plain streaming stores,
// then 4 per-slab block reductions + 4 atomics.
__global__ __launch_bounds__(256) void fused_copy_reduce(
    const float* __restrict__ in, float* __restrict__ out,
    float* __restrict__ out_energy) {
    const int b = blockIdx.x;
    const size_t base = (size_t)b * (SLABS_PER_BLOCK * HWSZ);
    const f4* __restrict__ in4 = (const f4*)(in + base);
    f4* __restrict__ out4 = (f4*)(out + base);
    const int t = threadIdx.x;

    // 16 independent loads, all in flight together.
    f4 v[16];
    #pragma unroll
    for (int s = 0; s < 4; ++s)
        #pragma unroll
        for (int j = 0; j < 4; ++j)
            v[s * 4 + j] = in4[s * 1024 + j * 256 + t];

    // Streaming copy-out (plain stores; fills hit 6.8 TB/s with these).
    #pragma unroll
    for (int s = 0; s < 4; ++s)
        #pragma unroll
        for (int j = 0; j < 4; ++j)
            out4[s * 1024 + j * 256 + t] = v[s * 4 + j];

    // Per-slab abs-sums (4 distinct channels per block).
    __shared__ float wsum[4][4];
    #pragma unroll
    for (int s = 0; s < 4; ++s) {
        f4 a = v[s * 4 + 0], bq = v[s * 4 + 1], cq = v[s * 4 + 2], dq = v[s * 4 + 3];
        float x = fabsf(a.x) + fabsf(a.y) + fabsf(a.z) + fabsf(a.w)
                + fabsf(bq.x) + fabsf(bq.y) + fabsf(bq.z) + fabsf(bq.w)
                + fabsf(cq.x) + fabsf(cq.y) + fabsf(cq.z) + fabsf(cq.w)
                + fabsf(dq.x) + fabsf(dq.y) + fabsf(dq.z) + fabsf(dq.w);
        #pragma unroll
        for (int off = 32; off > 0; off >>= 1) x += __shfl_down(x, off, 64);
        if ((t & 63) == 0) wsum[s][t >> 6] = x;
    }
    __syncthreads();
    if (t < 4) {   // thread t finalizes slab t of this block
        const int slab = b * SLABS_PER_BLOCK + t;
        const int c = slab & (CHANS - 1);
        const float tot = wsum[t][0] + wsum[t][1] + wsum[t][2] + wsum[t][3];
        atomicAdd(&out_energy[c], tot * INV_COUNT);
    }
}

extern "C" void kernel_launch(void* const* d_in, const int* in_sizes, int n_in,
                              void* d_out, int out_size, void* d_ws, size_t ws_size,
                              hipStream_t stream) {
    const float* data_in   = (const float*)d_in[0];
    const float* td_energy = (const float*)d_in[1];
    const float* td_hist   = (const float*)d_in[2];

    float* out_data   = (float*)d_out;
    float* out_energy = out_data + (size_t)NSLAB * HWSZ;
    float* out_hist   = out_energy + CHANS;

    // Node 1: seed small outputs (energy base + hist), ordered before atomics.
    init_small<<<(HIST_N + 255) / 256, 256, 0, stream>>>(
        td_energy, td_hist, out_energy, out_hist);

    // Node 2: the 268 MB streaming pass.
    fused_copy_reduce<<<NBLOCKS, 256, 0, stream>>>(data_in, out_data, out_energy);
}